// Round 12
// baseline (705.648 us; speedup 1.0000x reference)
//
#include <hip/hip_runtime.h>

#define H_ 128
#define T_ 1024
#define B_ 512
#define I_ 13
#define LOG2E 1.4426950408889634f

typedef _Float16 half8 __attribute__((ext_vector_type(8)));
typedef float float4_ __attribute__((ext_vector_type(4)));

static __device__ __forceinline__ float fast_rcp(float v) {
  return __builtin_amdgcn_rcpf(v);
}
static __device__ __forceinline__ float fast_exp2(float v) {
  return __builtin_amdgcn_exp2f(v);
}
static __device__ __forceinline__ float sigmoid_f(float v) {
  return fast_rcp(1.0f + fast_exp2(-LOG2E * v));
}
static __device__ __forceinline__ float tanh_f(float v) {
  return 2.0f * fast_rcp(1.0f + fast_exp2(-2.0f * LOG2E * v)) - 1.0f;
}

// R17 = R13 (615us, confirmed local optimum by R14/R15/R16 A/Bs) + FC
// balancing WITHOUT atomics / dynamic indexing (R14's idea, done right).
// R13's wave 7 issued 24 MFMAs vs 20 (others) -> SIMD3 matrix pipe ran
// 853cy vs 776, and the per-step barrier syncs the WG to the straggler
// (~78cy/step ~= 32us).
// Here: waves 4-7 each do ONE partial FC MFMA (own kc chunk, selected by
// wave-uniform STATIC branches -- rule #20 safe), writing 7 floats into a
// 512B double-buffered part[] ring (no atomics). Wave 3 combines row t-2's
// 4 partials (one ds_read_b128 + 3 adds + bias) at step t; post-loop
// combine covers the last row. MFMA issue: 41/SIMD on EVERY SIMD.
// Everything else is byte-for-byte R13: prologue seed + x-preacc all 4
// tiles in the tail, kc-outer/ti-inner ladder, end-of-loop activations.
// Structure: 256 WGs x 8 waves, 2 rows/WG, 2 waves/SIMD, weights
// VGPR-resident, zero vector-memory ops in the loop.
__global__ __launch_bounds__(512, 1) void lstm_fused(
    const float* __restrict__ x, const float* __restrict__ Wih,
    const float* __restrict__ Whh, const float* __restrict__ bih,
    const float* __restrict__ bhh, const float* __restrict__ Wfc,
    const float* __restrict__ bfc, float* __restrict__ out)
{
  // 64 KB: x(t) for both rows (f16), slots 13..15 zero (pad to k-chunk)
  __shared__ __align__(16) _Float16 xlds[T_][2][16];
  // 64 KB: logits ring, slot t holds logits for output row t (cols 0..6)
  __shared__ __align__(16) float lgring[T_][2][8];
  // 1.3 KB: double-buffered h (cols 0..127 used; stride 168 halfs)
  __shared__ __align__(16) _Float16 abuf[2][2][168];
  // 512 B: double-buffered FC partials [buf][brow][n16][kc]
  __shared__ __align__(16) float part[2][2][8][4];

  const int tid  = threadIdx.x;
  const int wave = tid >> 6;      // 0..7
  const int lane = tid & 63;
  const int n16  = lane & 15;
  const int quad = lane >> 4;
  const int wgb  = blockIdx.x * 2;

  // ---- W fragments: wave w owns tiles {g*8 + w : g=0..3} ----
  // (all 4 gates for col-group w -> cell update is lane-local)
  // B layout (16x16x32): lane holds B[k = quad*8 + j][n = n16]
  half8 wfrag[4][5];
  float biasv[4];
  #pragma unroll
  for (int ti = 0; ti < 4; ++ti) {
    const int tile = ti * 8 + wave;
    const int col  = tile * 16 + n16;
    biasv[ti] = bih[col] + bhh[col];
    #pragma unroll
    for (int kc = 0; kc < 5; ++kc) {
      half8 f;
      #pragma unroll
      for (int j = 0; j < 8; ++j) {
        const int k = kc * 32 + quad * 8 + j;
        float v = 0.0f;
        if (k < 128)            v = Whh[col * H_ + k];
        else if (k < 128 + I_)  v = Wih[col * I_ + (k - 128)];
        f[j] = (_Float16)v;
      }
      wfrag[ti][kc] = f;
    }
  }
  // FC chunk for this wave: wave w in {4..7} contributes kc = w-4
  half8 wfcw;
  {
    const int kcw = wave & 3;
    half8 f;
    #pragma unroll
    for (int j = 0; j < 8; ++j) {
      const int k = kcw * 32 + quad * 8 + j;
      f[j] = (_Float16)((n16 < 7) ? Wfc[n16 * H_ + k] : 0.0f);
    }
    wfcw = f;
  }
  const float biasfc = (n16 < 7) ? bfc[n16] : 0.0f;

  // ---- phase 0: preload all x for this WG into LDS (f16), zero pads ----
  for (int idx = tid; idx < T_ * 2 * 16; idx += 512) {
    const int t  = idx >> 5;
    const int rw = (idx >> 4) & 1;
    const int ii = idx & 15;
    float v = 0.0f;
    if (ii < I_) v = x[((size_t)t * B_ + wgb + rw) * I_ + ii];
    xlds[t][rw][ii] = (_Float16)v;
  }
  for (int idx = tid; idx < 2 * 2 * 168; idx += 512)
    ((_Float16*)abuf)[idx] = (_Float16)0.0f;
  __syncthreads();

  // cell state: quad q tracks D row 4q: rows 0,8 = batch 0; 4,12 = batch 1
  // (rows 8,12 are duplicates -> quads 2,3 mirror quads 0,1)
  float c_state = 0.0f;
  const bool aload = (n16 & 3) == 0;   // A rows 0,4,8,12
  const int  arow  = (n16 >> 2) & 1;   // rows 0,8 <- b0; 4,12 <- b1

  half8 af[4];
  half8 af4;
  {
    half8 z;
    #pragma unroll
    for (int j = 0; j < 8; ++j) z[j] = (_Float16)0.0f;
    #pragma unroll
    for (int kc = 0; kc < 4; ++kc) af[kc] = z;
    af4 = z;
  }
  if (aload && quad < 2)
    af4 = *(const half8*)&xlds[0][arow][quad * 8];

  float4_ acc[4];
  #pragma unroll
  for (int ti = 0; ti < 4; ++ti)
    #pragma unroll
    for (int r = 0; r < 4; ++r) acc[ti][r] = 0.0f;
  float4_ zero4;
  #pragma unroll
  for (int r = 0; r < 4; ++r) zero4[r] = 0.0f;

  // prologue: acc = bias + xg(t=0)  (x-part pre-accumulated, off-path)
  #pragma unroll
  for (int ti = 0; ti < 4; ++ti) acc[ti][0] = biasv[ti];
  #pragma unroll
  for (int ti = 0; ti < 4; ++ti)
    acc[ti] = __builtin_amdgcn_mfma_f32_16x16x32_f16(af4, wfrag[ti][4], acc[ti], 0, 0, 0);

  // ---- phase 1: the recurrence. No vector-memory ops in this loop. ----
  for (int t = 0; t <= T_; ++t) {
    // A fragments: h chunks 0..3 from abuf
    if (aload) {
      #pragma unroll
      for (int kc = 0; kc < 4; ++kc)
        af[kc] = *(const half8*)&abuf[t & 1][arow][kc * 32 + quad * 8];
    }

    // FC partials (waves 4-7): one MFMA each, static kc per wave.
    // Partials for output row t-1 land in part[t&1]; visible at t+1.
    if (wave >= 4 && t >= 1) {
      float4_ pacc;
      if (wave == 4)
        pacc = __builtin_amdgcn_mfma_f32_16x16x32_f16(af[0], wfcw, zero4, 0, 0, 0);
      else if (wave == 5)
        pacc = __builtin_amdgcn_mfma_f32_16x16x32_f16(af[1], wfcw, zero4, 0, 0, 0);
      else if (wave == 6)
        pacc = __builtin_amdgcn_mfma_f32_16x16x32_f16(af[2], wfcw, zero4, 0, 0, 0);
      else
        pacc = __builtin_amdgcn_mfma_f32_16x16x32_f16(af[3], wfcw, zero4, 0, 0, 0);
      if (lane < 32 && n16 < 7)
        part[t & 1][quad][n16][wave - 4] = pacc[0];
    }

    // FC combine (wave 3, no FC MFMA of its own): sum row t-2's partials.
    if (wave == 3 && t >= 2 && lane < 32 && n16 < 7) {
      const float4_ p = *(const float4_*)&part[(t - 1) & 1][quad][n16][0];
      lgring[t - 2][quad][n16] = ((p[0] + p[1]) + (p[2] + p[3])) + biasfc;
    }

    if (t < T_) {
      // h-dependent ladder: full interleave (kc outer, ti inner)
      #pragma unroll
      for (int kc = 0; kc < 4; ++kc) {
        #pragma unroll
        for (int ti = 0; ti < 4; ++ti)
          acc[ti] = __builtin_amdgcn_mfma_f32_16x16x32_f16(af[kc], wfrag[ti][kc], acc[ti], 0, 0, 0);
      }

      // prefetch next x-fragment (independent; hides under activations)
      if (aload && quad < 2 && t + 1 < T_)
        af4 = *(const half8*)&xlds[t + 1][arow][quad * 8];

      // cell update, FULL wave, fully lane-local (dup D rows quads 2,3)
      const float iv = sigmoid_f(acc[0][0]);
      const float fv = sigmoid_f(acc[1][0]);
      const float gg = tanh_f(acc[2][0]);
      const float ov = sigmoid_f(acc[3][0]);
      c_state = fv * c_state + iv * gg;
      const float hv = ov * tanh_f(c_state);
      if (lane < 32)
        abuf[(t + 1) & 1][quad][16 * wave + n16] = (_Float16)hv;

      // tail filler: seed + x-preacc all 4 tiles for step t+1 (keeps the
      // MFMA pipe busy under the activation VALU / barrier wait)
      #pragma unroll
      for (int ti = 0; ti < 4; ++ti) acc[ti][0] = biasv[ti];
      #pragma unroll
      for (int ti = 0; ti < 4; ++ti)
        acc[ti] = __builtin_amdgcn_mfma_f32_16x16x32_f16(af4, wfrag[ti][4], acc[ti], 0, 0, 0);
    }

    __syncthreads();
  }

  // combine the final row's partials (written at step T_, in part[T_&1])
  if (wave == 3 && lane < 32 && n16 < 7) {
    const float4_ p = *(const float4_*)&part[T_ & 1][quad][n16][0];
    lgring[T_ - 1][quad][n16] = ((p[0] + p[1]) + (p[2] + p[3])) + biasfc;
  }
  __syncthreads();

  // ---- phase 2: softmax of all 2048 logit rows -> out ----
  for (int r = tid; r < T_ * 2; r += 512) {
    const int t = r >> 1;
    const int b = r & 1;
    float lg[7];
    float mx = -3.0e38f;
    #pragma unroll
    for (int k = 0; k < 7; ++k) {
      lg[k] = lgring[t][b][k];
      mx = fmaxf(mx, lg[k]);
    }
    float s = 0.0f;
    #pragma unroll
    for (int k = 0; k < 7; ++k) {
      lg[k] = fast_exp2(LOG2E * (lg[k] - mx));
      s += lg[k];
    }
    const float rs = fast_rcp(s);
    float* op = &out[((size_t)t * B_ + wgb + b) * 7];
    #pragma unroll
    for (int k = 0; k < 7; ++k) op[k] = lg[k] * rs;
  }
}

extern "C" void kernel_launch(void* const* d_in, const int* in_sizes, int n_in,
                              void* d_out, int out_size, void* d_ws, size_t ws_size,
                              hipStream_t stream) {
  (void)in_sizes; (void)n_in; (void)out_size; (void)d_ws; (void)ws_size;
  const float* x   = (const float*)d_in[0];
  const float* Wih = (const float*)d_in[1];
  const float* Whh = (const float*)d_in[2];
  const float* bih = (const float*)d_in[3];
  const float* bhh = (const float*)d_in[4];
  const float* Wfc = (const float*)d_in[5];
  const float* bfc = (const float*)d_in[6];
  hipLaunchKernelGGL(lstm_fused, dim3(256), dim3(512), 0, stream,
                     x, Wih, Whh, bih, bhh, Wfc, bfc, (float*)d_out);
}

// Round 13
// 613.993 us; speedup vs baseline: 1.1493x; 1.1493x over previous
//
#include <hip/hip_runtime.h>

#define H_ 128
#define T_ 1024
#define B_ 512
#define I_ 13
#define LOG2E 1.4426950408889634f

typedef _Float16 half8 __attribute__((ext_vector_type(8)));
typedef float float4_ __attribute__((ext_vector_type(4)));

static __device__ __forceinline__ float fast_rcp(float v) {
  return __builtin_amdgcn_rcpf(v);
}
static __device__ __forceinline__ float fast_exp2(float v) {
  return __builtin_amdgcn_exp2f(v);
}
static __device__ __forceinline__ float sigmoid_f(float v) {
  return fast_rcp(1.0f + fast_exp2(-LOG2E * v));
}
static __device__ __forceinline__ float tanh_f(float v) {
  return 2.0f * fast_rcp(1.0f + fast_exp2(-2.0f * LOG2E * v)) - 1.0f;
}

// R18 = R13 (615us) + ONE change: wave 7's FC moved head -> tail.
// R16/R17 post-mortems refined the model: s_barrier waits on memory
// counters only, NOT MFMA completion -- tail-issued MFMAs drain across
// the barrier for free (why R13's tail x-preacc works and R16's
// head-fill hurt: head MFMAs' C-results block the ladder).
// R13's FC sat in wave 7's HEAD: 4 chained MFMAs issued before the gate
// ladder delayed wave 7's ladder -> activations -> h-write by ~50-70cy,
// and the barrier syncs the WG to wave 7 (the straggler).
// Now: tail of step t (t>=1, wave 7): after h-write + x-preacc, seed
// accf and issue the 4 FC MFMAs on the still-live af (= h(t), logits row
// t-1); they complete during the barrier. Head of step t (t>=2): write
// accf[0] (long done) to lgring[t-2] -- one masked ds_write. Epilogue
// covers rows T-2 (harvest) and T-1 (FC on af(T_)).
// Everything else byte-for-byte R13. No redistribution (R17's mistake),
// no atomics, no dynamic indexing; arithmetic identical.
__global__ __launch_bounds__(512, 1) void lstm_fused(
    const float* __restrict__ x, const float* __restrict__ Wih,
    const float* __restrict__ Whh, const float* __restrict__ bih,
    const float* __restrict__ bhh, const float* __restrict__ Wfc,
    const float* __restrict__ bfc, float* __restrict__ out)
{
  // 64 KB: x(t) for both rows (f16), slots 13..15 zero (pad to k-chunk)
  __shared__ __align__(16) _Float16 xlds[T_][2][16];
  // 64 KB: logits ring, slot t holds logits for output row t (cols 0..6)
  __shared__ __align__(16) float lgring[T_][2][8];
  // 1.3 KB: double-buffered h (cols 0..127 used; stride 168 halfs)
  __shared__ __align__(16) _Float16 abuf[2][2][168];

  const int tid  = threadIdx.x;
  const int wave = tid >> 6;      // 0..7
  const int lane = tid & 63;
  const int n16  = lane & 15;
  const int quad = lane >> 4;
  const int wgb  = blockIdx.x * 2;

  // ---- W fragments: wave w owns tiles {g*8 + w : g=0..3} ----
  // (all 4 gates for col-group w -> cell update is lane-local)
  // B layout (16x16x32): lane holds B[k = quad*8 + j][n = n16]
  half8 wfrag[4][5];
  float biasv[4];
  #pragma unroll
  for (int ti = 0; ti < 4; ++ti) {
    const int tile = ti * 8 + wave;
    const int col  = tile * 16 + n16;
    biasv[ti] = bih[col] + bhh[col];
    #pragma unroll
    for (int kc = 0; kc < 5; ++kc) {
      half8 f;
      #pragma unroll
      for (int j = 0; j < 8; ++j) {
        const int k = kc * 32 + quad * 8 + j;
        float v = 0.0f;
        if (k < 128)            v = Whh[col * H_ + k];
        else if (k < 128 + I_)  v = Wih[col * I_ + (k - 128)];
        f[j] = (_Float16)v;
      }
      wfrag[ti][kc] = f;
    }
  }
  // FC tile (consumed by wave 7; loaded uniformly), k < 128 -> 4 chunks
  half8 wfc[4];
  const float biasfc = (n16 < 7) ? bfc[n16] : 0.0f;
  #pragma unroll
  for (int kc = 0; kc < 4; ++kc) {
    half8 f;
    #pragma unroll
    for (int j = 0; j < 8; ++j) {
      const int k = kc * 32 + quad * 8 + j;
      f[j] = (_Float16)((n16 < 7) ? Wfc[n16 * H_ + k] : 0.0f);
    }
    wfc[kc] = f;
  }

  // ---- phase 0: preload all x for this WG into LDS (f16), zero pads ----
  for (int idx = tid; idx < T_ * 2 * 16; idx += 512) {
    const int t  = idx >> 5;
    const int rw = (idx >> 4) & 1;
    const int ii = idx & 15;
    float v = 0.0f;
    if (ii < I_) v = x[((size_t)t * B_ + wgb + rw) * I_ + ii];
    xlds[t][rw][ii] = (_Float16)v;
  }
  for (int idx = tid; idx < 2 * 2 * 168; idx += 512)
    ((_Float16*)abuf)[idx] = (_Float16)0.0f;
  __syncthreads();

  // cell state: quad q tracks D row 4q: rows 0,8 = batch 0; 4,12 = batch 1
  // (rows 8,12 are duplicates -> quads 2,3 mirror quads 0,1)
  float c_state = 0.0f;
  const bool aload = (n16 & 3) == 0;   // A rows 0,4,8,12
  const int  arow  = (n16 >> 2) & 1;   // rows 0,8 <- b0; 4,12 <- b1

  half8 af[4];
  half8 af4;
  {
    half8 z;
    #pragma unroll
    for (int j = 0; j < 8; ++j) z[j] = (_Float16)0.0f;
    #pragma unroll
    for (int kc = 0; kc < 4; ++kc) af[kc] = z;
    af4 = z;
  }
  if (aload && quad < 2)
    af4 = *(const half8*)&xlds[0][arow][quad * 8];

  float4_ acc[4];
  #pragma unroll
  for (int ti = 0; ti < 4; ++ti)
    #pragma unroll
    for (int r = 0; r < 4; ++r) acc[ti][r] = 0.0f;
  float4_ accf;
  #pragma unroll
  for (int r = 0; r < 4; ++r) accf[r] = 0.0f;

  // prologue: acc = bias + xg(t=0)  (x-part pre-accumulated, off-path)
  #pragma unroll
  for (int ti = 0; ti < 4; ++ti) acc[ti][0] = biasv[ti];
  #pragma unroll
  for (int ti = 0; ti < 4; ++ti)
    acc[ti] = __builtin_amdgcn_mfma_f32_16x16x32_f16(af4, wfrag[ti][4], acc[ti], 0, 0, 0);

  // ---- phase 1: the recurrence. No vector-memory ops in this loop. ----
  for (int t = 0; t <= T_; ++t) {
    // A fragments: h chunks 0..3 from abuf
    if (aload) {
      #pragma unroll
      for (int kc = 0; kc < 4; ++kc)
        af[kc] = *(const half8*)&abuf[t & 1][arow][kc * 32 + quad * 8];
    }

    // FC harvest (wave 7): tail-FC of step t-1 (row t-2) completed
    // during the barrier -- just store it. ~10cy, no MFMA wait.
    if (wave == 7 && t >= 2 && lane < 32 && n16 < 7)
      lgring[t - 2][quad][n16] = accf[0];

    if (t < T_) {
      // h-dependent ladder: full interleave (kc outer, ti inner) --
      // wave 7's ladder now starts as early as everyone else's.
      #pragma unroll
      for (int kc = 0; kc < 4; ++kc) {
        #pragma unroll
        for (int ti = 0; ti < 4; ++ti)
          acc[ti] = __builtin_amdgcn_mfma_f32_16x16x32_f16(af[kc], wfrag[ti][kc], acc[ti], 0, 0, 0);
      }

      // prefetch next x-fragment (independent; hides under activations)
      if (aload && quad < 2 && t + 1 < T_)
        af4 = *(const half8*)&xlds[t + 1][arow][quad * 8];

      // cell update, FULL wave, fully lane-local (dup D rows quads 2,3)
      const float iv = sigmoid_f(acc[0][0]);
      const float fv = sigmoid_f(acc[1][0]);
      const float gg = tanh_f(acc[2][0]);
      const float ov = sigmoid_f(acc[3][0]);
      c_state = fv * c_state + iv * gg;
      const float hv = ov * tanh_f(c_state);
      if (lane < 32)
        abuf[(t + 1) & 1][quad][16 * wave + n16] = (_Float16)hv;

      // tail filler: seed + x-preacc all 4 tiles for step t+1 (keeps the
      // MFMA pipe busy under the activation VALU; completes over barrier)
      #pragma unroll
      for (int ti = 0; ti < 4; ++ti) acc[ti][0] = biasv[ti];
      #pragma unroll
      for (int ti = 0; ti < 4; ++ti)
        acc[ti] = __builtin_amdgcn_mfma_f32_16x16x32_f16(af4, wfrag[ti][4], acc[ti], 0, 0, 0);

      // tail FC (wave 7, t>=1): af still holds h(t) -> logits row t-1.
      // Issues into the idle pipe; completes during the barrier; the
      // result is harvested at the next step's head.
      if (wave == 7 && t >= 1) {
        accf[0] = biasfc;
        #pragma unroll
        for (int kc = 0; kc < 4; ++kc)
          accf = __builtin_amdgcn_mfma_f32_16x16x32_f16(af[kc], wfc[kc], accf, 0, 0, 0);
      }
    }

    __syncthreads();
  }

  // epilogue (wave 7): harvest tail-FC of step T_-1 (row T_-2), then
  // compute + store the final row T_-1 from af = h(T_) (loaded at t=T_).
  if (wave == 7) {
    if (lane < 32 && n16 < 7)
      lgring[T_ - 2][quad][n16] = accf[0];
    accf[0] = biasfc;
    #pragma unroll
    for (int kc = 0; kc < 4; ++kc)
      accf = __builtin_amdgcn_mfma_f32_16x16x32_f16(af[kc], wfc[kc], accf, 0, 0, 0);
    if (lane < 32 && n16 < 7)
      lgring[T_ - 1][quad][n16] = accf[0];
  }
  __syncthreads();

  // ---- phase 2: softmax of all 2048 logit rows -> out ----
  for (int r = tid; r < T_ * 2; r += 512) {
    const int t = r >> 1;
    const int b = r & 1;
    float lg[7];
    float mx = -3.0e38f;
    #pragma unroll
    for (int k = 0; k < 7; ++k) {
      lg[k] = lgring[t][b][k];
      mx = fmaxf(mx, lg[k]);
    }
    float s = 0.0f;
    #pragma unroll
    for (int k = 0; k < 7; ++k) {
      lg[k] = fast_exp2(LOG2E * (lg[k] - mx));
      s += lg[k];
    }
    const float rs = fast_rcp(s);
    float* op = &out[((size_t)t * B_ + wgb + b) * 7];
    #pragma unroll
    for (int k = 0; k < 7; ++k) op[k] = lg[k] * rs;
  }
}

extern "C" void kernel_launch(void* const* d_in, const int* in_sizes, int n_in,
                              void* d_out, int out_size, void* d_ws, size_t ws_size,
                              hipStream_t stream) {
  (void)in_sizes; (void)n_in; (void)out_size; (void)d_ws; (void)ws_size;
  const float* x   = (const float*)d_in[0];
  const float* Wih = (const float*)d_in[1];
  const float* Whh = (const float*)d_in[2];
  const float* bih = (const float*)d_in[3];
  const float* bhh = (const float*)d_in[4];
  const float* Wfc = (const float*)d_in[5];
  const float* bfc = (const float*)d_in[6];
  hipLaunchKernelGGL(lstm_fused, dim3(256), dim3(512), 0, stream,
                     x, Wih, Whh, bih, bhh, Wfc, bfc, (float*)d_out);
}